// Round 10
// baseline (84.051 us; speedup 1.0000x reference)
//
#include <hip/hip_runtime.h>
#include <hip/hip_fp16.h>

typedef _Float16 half8 __attribute__((ext_vector_type(8)));
typedef _Float16 half2v __attribute__((ext_vector_type(2)));
typedef float f32x16 __attribute__((ext_vector_type(16)));

#define BM 128
#define BN 64
#define BK 64
#define THREADS 256
#define LDS_TILE (BM * BK * 2)   // 16 KB per buffer, 32 KB total

__device__ inline unsigned pkrtz(float lo, float hi) {
  return __builtin_bit_cast(unsigned, __builtin_amdgcn_cvt_pkrtz(lo, hi));
}

// raw barrier: lgkm drain only — all global loads stay in flight
#define BAR() do { \
  asm volatile("s_waitcnt lgkmcnt(0)" ::: "memory"); \
  __builtin_amdgcn_s_barrier(); \
} while (0)

__global__ void init_out_kernel(const float* __restrict__ bias,
                                float* __restrict__ out, int MN, int N) {
  int i = (blockIdx.x * blockDim.x + threadIdx.x) * 4;
  if (i < MN) *(float4*)(out + i) = *(const float4*)(bias + (i % N));
}

__global__ void reduce_kernel(const float* __restrict__ ws,
                              const float* __restrict__ bias,
                              float* __restrict__ out, int MN, int N, int S) {
  int i = (blockIdx.x * blockDim.x + threadIdx.x) * 4;
  if (i >= MN) return;
  float4 a = *(const float4*)(bias + (i % N));
  for (int z = 0; z < S; ++z) {
    float4 p = *(const float4*)(ws + (size_t)z * MN + i);
    a.x += p.x; a.y += p.y; a.z += p.z; a.w += p.w;
  }
  *(float4*)(out + i) = a;
}

struct Bs {
  unsigned w[4];       // 4 packed qweight words (this lane-half's k-octets)
  unsigned zr, sr;     // fp16(1025+z) x2, fp16(s) x2
};

__device__ inline half8 dequant(unsigned w, unsigned zr, unsigned sr) {
  half2v zh = __builtin_bit_cast(half2v, zr);
  half2v sh = __builtin_bit_cast(half2v, sr);
  unsigned u0 = (w & 0x000F000Fu) | 0x64006400u;          // k-pair (0,4)
  unsigned u1 = ((w >> 4) & 0x000F000Fu) | 0x64006400u;   // (1,5)
  unsigned u2 = ((w >> 8) & 0x000F000Fu) | 0x64006400u;   // (2,6)
  unsigned u3 = ((w >> 12) & 0x000F000Fu) | 0x64006400u;  // (3,7)
  uint4 r;
  r.x = __builtin_bit_cast(unsigned, (half2v)((__builtin_bit_cast(half2v, u0) - zh) * sh));
  r.y = __builtin_bit_cast(unsigned, (half2v)((__builtin_bit_cast(half2v, u1) - zh) * sh));
  r.z = __builtin_bit_cast(unsigned, (half2v)((__builtin_bit_cast(half2v, u2) - zh) * sh));
  r.w = __builtin_bit_cast(unsigned, (half2v)((__builtin_bit_cast(half2v, u3) - zh) * sh));
  return __builtin_bit_cast(half8, r);
}

template <int NT>
__global__ __launch_bounds__(THREADS) void qgemm_kernel(
    const float* __restrict__ x, const int* __restrict__ qw,
    const int* __restrict__ qz, const float* __restrict__ sc,
    float* __restrict__ target, int N, int K, int use_ws) {
  __shared__ __align__(16) unsigned char smem[2 * LDS_TILE];  // 32 KB
  const int tid = threadIdx.x;
  const int n0 = blockIdx.x * BN;
  const int z = blockIdx.z;
  const int KC = NT * BK;
  const int kbase = z * KC;
  const int lane = tid & 63;
  const int wid = tid >> 6;          // 0..3
  const int wr = wid >> 1;           // 0..1 (M-half, 64 rows)
  const int wc = wid & 1;            // 0..1 (N-half, 32 cols)
  const int l31 = lane & 31;
  const int l5 = lane >> 5;
  const int N8 = N >> 3;
  const int kqb = kbase >> 3;        // packed-row base

  f32x16 acc0 = {}, acc1 = {};

  // A staging: 2 threads/row; arow 0..127, half ah -> 32 k (4 units)
  const int arow = tid >> 1;
  const int ah = tid & 1;
  // this wave's output column
  const int c0 = n0 + wc * 32 + l31;

  float4 areg[8];
  auto LOADA = [&](int t) {
    const float* src = x + arow * K + kbase + t * BK + ah * 32;
#pragma unroll
    for (int j = 0; j < 8; ++j) areg[j] = *(const float4*)(src + 4 * j);
  };

  // unit u holds k [8u,8u+8) as pairs (k+i, k+i+4); swizzle u ^= row&7
  auto STOREA = [&](int buf) {
    unsigned char* base = smem + buf * LDS_TILE;
#pragma unroll
    for (int j = 0; j < 4; ++j) {
      uint4 q;
      q.x = pkrtz(areg[2 * j].x, areg[2 * j + 1].x);
      q.y = pkrtz(areg[2 * j].y, areg[2 * j + 1].y);
      q.z = pkrtz(areg[2 * j].z, areg[2 * j + 1].z);
      q.w = pkrtz(areg[2 * j].w, areg[2 * j + 1].w);
      int u = ah * 4 + j;
      *(uint4*)(base + arow * 128 + ((u ^ (arow & 7)) << 4)) = q;
    }
  };

  auto LOADB = [&](int t, Bs& b) {
    const int* q0 = qw + (kqb + t * 8 + l5) * N + c0;
#pragma unroll
    for (int s = 0; s < 4; ++s) b.w[s] = (unsigned)q0[2 * s * N];
    int g = (kbase + t * BK) >> 7;
    int zw = qz[g * N8 + (c0 >> 3)];
    b.zr = (0x6401u + (unsigned)((zw >> ((c0 & 7) * 4)) & 0xF)) * 0x00010001u;
    float s0 = sc[g * N + c0];
    b.sr = pkrtz(s0, s0);
  };

  auto COMPUTE = [&](int buf, const Bs& b) {
    unsigned char* base = smem + buf * LDS_TILE;
#pragma unroll
    for (int s = 0; s < 4; ++s) {
      int u = 2 * s + l5;
      int row0 = wr * 64 + l31;
      half8 a0 = *(half8*)(base + row0 * 128 + ((u ^ (row0 & 7)) << 4));
      int row1 = row0 + 32;
      half8 a1 = *(half8*)(base + row1 * 128 + ((u ^ (row1 & 7)) << 4));
      half8 bf = dequant(b.w[s], b.zr, b.sr);
      acc0 = __builtin_amdgcn_mfma_f32_32x32x16_f16(a0, bf, acc0, 0, 0, 0);
      acc1 = __builtin_amdgcn_mfma_f32_32x32x16_f16(a1, bf, acc1, 0, 0, 0);
    }
  };

  // prologue
  Bs b0, b1;
  LOADA(0);
  LOADB(0, b0);
  STOREA(0);
  LOADA(1);
  LOADB(1, b1);
  __syncthreads();

  // main loop, fully unrolled: 1 barrier/phase; B never touches LDS
#pragma unroll
  for (int t = 0; t < NT; t += 2) {
    STOREA(1);                                   // tile t+1 -> buf1
    { int tn = t + 2 < NT ? t + 2 : NT - 1; LOADA(tn); }
    COMPUTE(0, b0);
    { int tn = t + 2 < NT ? t + 2 : NT - 1; LOADB(tn, b0); }
    BAR();

    STOREA(0);                                   // tile t+2 -> buf0
    { int tn = t + 3 < NT ? t + 3 : NT - 1; LOADA(tn); }
    COMPUTE(1, b1);
    { int tn = t + 3 < NT ? t + 3 : NT - 1; LOADB(tn, b1); }
    BAR();
  }

  // epilogue: C/D (32x32): col=lane&31, row=(r&3)+8*(r>>2)+4*(lane>>5)
  if (use_ws) {
    float* o = target + (size_t)z * (size_t)BM * N;
#pragma unroll
    for (int r = 0; r < 16; ++r) {
      int gm = wr * 64 + (r & 3) + 8 * (r >> 2) + 4 * l5;
      o[(size_t)gm * N + c0] = acc0[r];
      o[(size_t)(gm + 32) * N + c0] = acc1[r];
    }
  } else {
#pragma unroll
    for (int r = 0; r < 16; ++r) {
      int gm = wr * 64 + (r & 3) + 8 * (r >> 2) + 4 * l5;
      unsafeAtomicAdd(&target[(size_t)gm * N + c0], acc0[r]);
      unsafeAtomicAdd(&target[(size_t)(gm + 32) * N + c0], acc1[r]);
    }
  }
}

extern "C" void kernel_launch(void* const* d_in, const int* in_sizes, int n_in,
                              void* d_out, int out_size, void* d_ws, size_t ws_size,
                              hipStream_t stream) {
  const float* x = (const float*)d_in[0];
  const int* qw = (const int*)d_in[1];
  const int* qz = (const int*)d_in[2];
  const float* sc = (const float*)d_in[3];
  const float* bias = (const float*)d_in[4];
  float* out = (float*)d_out;

  int N = in_sizes[4];
  int K = (in_sizes[1] / N) * 8;
  int M = in_sizes[0] / K;           // == BM == 128
  int MN = M * N;
  size_t slice = (size_t)MN * 4;

  int S = 0;
  if (ws_size >= 8 * slice) S = 8;
  else if (ws_size >= 4 * slice) S = 4;
  else if (ws_size >= 2 * slice) S = 2;

  if (S == 8) {
    dim3 grid(N / BN, 1, 8);
    qgemm_kernel<8><<<grid, THREADS, 0, stream>>>(x, qw, qz, sc, (float*)d_ws, N, K, 1);
    reduce_kernel<<<(MN / 4 + 255) / 256, 256, 0, stream>>>(
        (const float*)d_ws, bias, out, MN, N, 8);
  } else if (S == 4) {
    dim3 grid(N / BN, 1, 4);
    qgemm_kernel<16><<<grid, THREADS, 0, stream>>>(x, qw, qz, sc, (float*)d_ws, N, K, 1);
    reduce_kernel<<<(MN / 4 + 255) / 256, 256, 0, stream>>>(
        (const float*)d_ws, bias, out, MN, N, 4);
  } else if (S == 2) {
    dim3 grid(N / BN, 1, 2);
    qgemm_kernel<32><<<grid, THREADS, 0, stream>>>(x, qw, qz, sc, (float*)d_ws, N, K, 1);
    reduce_kernel<<<(MN / 4 + 255) / 256, 256, 0, stream>>>(
        (const float*)d_ws, bias, out, MN, N, 2);
  } else {
    init_out_kernel<<<(MN / 4 + 255) / 256, 256, 0, stream>>>(bias, out, MN, N);
    dim3 grid(N / BN, 1, 8);
    qgemm_kernel<8><<<grid, THREADS, 0, stream>>>(x, qw, qz, sc, out, N, K, 0);
  }
}

// Round 11
// 59.592 us; speedup vs baseline: 1.4104x; 1.4104x over previous
//
#include <hip/hip_runtime.h>
#include <hip/hip_fp16.h>

typedef _Float16 half8 __attribute__((ext_vector_type(8)));
typedef _Float16 half2v __attribute__((ext_vector_type(2)));
typedef float f32x16 __attribute__((ext_vector_type(16)));

__device__ inline unsigned pkrtz(float lo, float hi) {
  return __builtin_bit_cast(unsigned, __builtin_amdgcn_cvt_pkrtz(lo, hi));
}

// int4 word (8 nibbles) -> 8 fp16 in pair order [(0,4),(1,5),(2,6),(3,7)]
__device__ inline half8 dequant(unsigned w, unsigned zr, unsigned sr) {
  half2v zh = __builtin_bit_cast(half2v, zr);
  half2v sh = __builtin_bit_cast(half2v, sr);
  unsigned u0 = (w & 0x000F000Fu) | 0x64006400u;
  unsigned u1 = ((w >> 4) & 0x000F000Fu) | 0x64006400u;
  unsigned u2 = ((w >> 8) & 0x000F000Fu) | 0x64006400u;
  unsigned u3 = ((w >> 12) & 0x000F000Fu) | 0x64006400u;
  uint4 r;
  r.x = __builtin_bit_cast(unsigned, (half2v)((__builtin_bit_cast(half2v, u0) - zh) * sh));
  r.y = __builtin_bit_cast(unsigned, (half2v)((__builtin_bit_cast(half2v, u1) - zh) * sh));
  r.z = __builtin_bit_cast(unsigned, (half2v)((__builtin_bit_cast(half2v, u2) - zh) * sh));
  r.w = __builtin_bit_cast(unsigned, (half2v)((__builtin_bit_cast(half2v, u3) - zh) * sh));
  return __builtin_bit_cast(half8, r);
}

// x fp32 -> fp16 with per-octet pair permutation [(0,4),(1,5),(2,6),(3,7)]
__global__ void xhalf_kernel(const float* __restrict__ x,
                             uint4* __restrict__ xh, int total8) {
  int i = blockIdx.x * blockDim.x + threadIdx.x;
  if (i >= total8) return;
  const float* src = x + (size_t)i * 8;
  float4 f0 = *(const float4*)src;
  float4 f1 = *(const float4*)(src + 4);
  uint4 q;
  q.x = pkrtz(f0.x, f1.x); q.y = pkrtz(f0.y, f1.y);
  q.z = pkrtz(f0.z, f1.z); q.w = pkrtz(f0.w, f1.w);
  xh[i] = q;
}

__global__ void init_out_kernel(const float* __restrict__ bias,
                                float* __restrict__ out, int MN, int N) {
  int i = (blockIdx.x * blockDim.x + threadIdx.x) * 4;
  if (i < MN) *(float4*)(out + i) = *(const float4*)(bias + (i % N));
}

__global__ void reduce_kernel(const float* __restrict__ ws,
                              const float* __restrict__ bias,
                              float* __restrict__ out, int MN, int N, int S) {
  int i = (blockIdx.x * blockDim.x + threadIdx.x) * 4;
  if (i >= MN) return;
  float4 a = *(const float4*)(bias + (i % N));
  for (int z = 0; z < S; ++z) {
    float4 p = *(const float4*)(ws + (size_t)z * MN + i);
    a.x += p.x; a.y += p.y; a.z += p.z; a.w += p.w;
  }
  *(float4*)(out + i) = a;
}

// Barrier-free wave-level GEMM: no LDS, no __syncthreads.
// Block = 4 independent waves (2x2), wave tile 64M x 64N of 32x32x16 MFMAs.
// B (qweight) dequantized straight into register fragments; A read as 16B
// fragments from pre-converted fp16 x (permuted to match dequant pair order).
template <int NT, int USE_WS, int XH>
__global__ __launch_bounds__(256, 3) void qgemm_kernel(
    const float* __restrict__ x, const _Float16* __restrict__ xh,
    const int* __restrict__ qw, const int* __restrict__ qz,
    const float* __restrict__ sc, float* __restrict__ target, int N, int K) {
  const int tid = threadIdx.x;
  const int lane = tid & 63;
  const int wid = tid >> 6;          // 0..3
  const int wr = wid >> 1;           // M half (64 rows)
  const int wc = wid & 1;            // N half (64 cols)
  const int l31 = lane & 31;
  const int l5 = lane >> 5;
  const int z = blockIdx.z;
  const int KC = NT * 64;
  const int kbase = z * KC;
  const int kqb = kbase >> 3;
  const int N8 = N >> 3;
  const int n0 = blockIdx.x * 128;
  const int c0 = n0 + wc * 64 + l31;
  const int c1 = c0 + 32;
  const int row0 = wr * 64 + l31;    // fi=0 row; fi=1 is +32

  f32x16 acc00 = {}, acc01 = {}, acc10 = {}, acc11 = {};

  struct BT { unsigned w0[4], w1[4]; unsigned zr0, sr0, zr1, sr1; };

  auto LOADB = [&](int t, BT& b) {
    const int* q0 = qw + (size_t)(kqb + t * 8 + l5) * N;
#pragma unroll
    for (int s = 0; s < 4; ++s) {
      b.w0[s] = (unsigned)q0[2 * s * N + c0];
      b.w1[s] = (unsigned)q0[2 * s * N + c1];
    }
    int g = (kbase + t * 64) >> 7;
    int zw0 = qz[g * N8 + (c0 >> 3)];
    int zw1 = qz[g * N8 + (c1 >> 3)];
    b.zr0 = (0x6401u + ((unsigned)(zw0 >> ((c0 & 7) * 4)) & 0xF)) * 0x00010001u;
    b.zr1 = (0x6401u + ((unsigned)(zw1 >> ((c1 & 7) * 4)) & 0xF)) * 0x00010001u;
    float s0 = sc[g * N + c0], s1 = sc[g * N + c1];
    b.sr0 = pkrtz(s0, s0);
    b.sr1 = pkrtz(s1, s1);
  };

  auto LOADAF = [&](int t, int s, half8& a0, half8& a1) {
    int k = kbase + t * 64 + s * 16 + l5 * 8;
    if (XH) {
      a0 = *(const half8*)(xh + (size_t)row0 * K + k);
      a1 = *(const half8*)(xh + (size_t)(row0 + 32) * K + k);
    } else {
      const float* p0 = x + (size_t)row0 * K + k;
      const float* p1 = x + (size_t)(row0 + 32) * K + k;
      float4 f0 = *(const float4*)p0, f1 = *(const float4*)(p0 + 4);
      float4 g0 = *(const float4*)p1, g1 = *(const float4*)(p1 + 4);
      uint4 qa, qb;
      qa.x = pkrtz(f0.x, f1.x); qa.y = pkrtz(f0.y, f1.y);
      qa.z = pkrtz(f0.z, f1.z); qa.w = pkrtz(f0.w, f1.w);
      qb.x = pkrtz(g0.x, g1.x); qb.y = pkrtz(g0.y, g1.y);
      qb.z = pkrtz(g0.z, g1.z); qb.w = pkrtz(g0.w, g1.w);
      a0 = __builtin_bit_cast(half8, qa);
      a1 = __builtin_bit_cast(half8, qb);
    }
  };

  auto TILE = [&](const BT& b, int t) {
#pragma unroll
    for (int s = 0; s < 4; ++s) {
      half8 a0, a1;
      LOADAF(t, s, a0, a1);
      half8 bf0 = dequant(b.w0[s], b.zr0, b.sr0);
      half8 bf1 = dequant(b.w1[s], b.zr1, b.sr1);
      acc00 = __builtin_amdgcn_mfma_f32_32x32x16_f16(a0, bf0, acc00, 0, 0, 0);
      acc01 = __builtin_amdgcn_mfma_f32_32x32x16_f16(a0, bf1, acc01, 0, 0, 0);
      acc10 = __builtin_amdgcn_mfma_f32_32x32x16_f16(a1, bf0, acc10, 0, 0, 0);
      acc11 = __builtin_amdgcn_mfma_f32_32x32x16_f16(a1, bf1, acc11, 0, 0, 0);
    }
  };

  BT bA, bB;
  LOADB(0, bA);
  LOADB(1, bB);
#pragma unroll
  for (int t = 0; t < NT; t += 2) {
    TILE(bA, t);
    if (t + 2 < NT) LOADB(t + 2, bA);
    TILE(bB, t + 1);
    if (t + 3 < NT) LOADB(t + 3, bB);
  }

  // epilogue: C/D (32x32): col=lane&31, row=(r&3)+8*(r>>2)+4*(lane>>5)
  if (USE_WS) {
    float* o = target + (size_t)z * 128 * N;
#pragma unroll
    for (int r = 0; r < 16; ++r) {
      int gm = wr * 64 + (r & 3) + 8 * (r >> 2) + 4 * l5;
      o[(size_t)gm * N + c0] = acc00[r];
      o[(size_t)gm * N + c1] = acc01[r];
      o[(size_t)(gm + 32) * N + c0] = acc10[r];
      o[(size_t)(gm + 32) * N + c1] = acc11[r];
    }
  } else {
#pragma unroll
    for (int r = 0; r < 16; ++r) {
      int gm = wr * 64 + (r & 3) + 8 * (r >> 2) + 4 * l5;
      unsafeAtomicAdd(&target[(size_t)gm * N + c0], acc00[r]);
      unsafeAtomicAdd(&target[(size_t)gm * N + c1], acc01[r]);
      unsafeAtomicAdd(&target[(size_t)(gm + 32) * N + c0], acc10[r]);
      unsafeAtomicAdd(&target[(size_t)(gm + 32) * N + c1], acc11[r]);
    }
  }
}

extern "C" void kernel_launch(void* const* d_in, const int* in_sizes, int n_in,
                              void* d_out, int out_size, void* d_ws, size_t ws_size,
                              hipStream_t stream) {
  const float* x = (const float*)d_in[0];
  const int* qw = (const int*)d_in[1];
  const int* qz = (const int*)d_in[2];
  const float* sc = (const float*)d_in[3];
  const float* bias = (const float*)d_in[4];
  float* out = (float*)d_out;

  int N = in_sizes[4];
  int K = (in_sizes[1] / N) * 8;
  int M = in_sizes[0] / K;           // == 128
  int MN = M * N;
  int MK = M * K;
  size_t slice = (size_t)MN * 4;

  int S = 0;
  if (ws_size >= 8 * slice) S = 8;
  else if (ws_size >= 4 * slice) S = 4;
  else if (ws_size >= 2 * slice) S = 2;

  if (S > 0) {
    // stage fp16 x in the head of d_out (1 MB); reduce overwrites all of d_out
    _Float16* xh = (_Float16*)d_out;
    xhalf_kernel<<<(MK / 8 + 255) / 256, 256, 0, stream>>>(x, (uint4*)xh, MK / 8);
    if (S == 8) {
      dim3 grid(N / 128, 1, 8);
      qgemm_kernel<8, 1, 1><<<grid, 256, 0, stream>>>(x, xh, qw, qz, sc, (float*)d_ws, N, K);
    } else if (S == 4) {
      dim3 grid(N / 128, 1, 4);
      qgemm_kernel<16, 1, 1><<<grid, 256, 0, stream>>>(x, xh, qw, qz, sc, (float*)d_ws, N, K);
    } else {
      dim3 grid(N / 128, 1, 2);
      qgemm_kernel<32, 1, 1><<<grid, 256, 0, stream>>>(x, xh, qw, qz, sc, (float*)d_ws, N, K);
    }
    reduce_kernel<<<(MN / 4 + 255) / 256, 256, 0, stream>>>(
        (const float*)d_ws, bias, out, MN, N, S);
  } else {
    // no workspace: atomic accumulate, on-the-fly A conversion
    init_out_kernel<<<(MN / 4 + 255) / 256, 256, 0, stream>>>(bias, out, MN, N);
    dim3 grid(N / 128, 1, 8);
    qgemm_kernel<8, 0, 0><<<grid, 256, 0, stream>>>(x, (const _Float16*)nullptr,
                                                    qw, qz, sc, out, N, K);
  }
}

// Round 12
// 49.180 us; speedup vs baseline: 1.7090x; 1.2117x over previous
//
#include <hip/hip_runtime.h>
#include <hip/hip_fp16.h>

typedef _Float16 half8 __attribute__((ext_vector_type(8)));
typedef _Float16 half2v __attribute__((ext_vector_type(2)));
typedef float f32x16 __attribute__((ext_vector_type(16)));

__device__ inline unsigned pkrtz(float lo, float hi) {
  return __builtin_bit_cast(unsigned, __builtin_amdgcn_cvt_pkrtz(lo, hi));
}

// int4 word (8 nibbles) -> 8 fp16 in pair order [(0,4),(1,5),(2,6),(3,7)]
__device__ inline half8 dequant(unsigned w, unsigned zr, unsigned sr) {
  half2v zh = __builtin_bit_cast(half2v, zr);
  half2v sh = __builtin_bit_cast(half2v, sr);
  unsigned u0 = (w & 0x000F000Fu) | 0x64006400u;
  unsigned u1 = ((w >> 4) & 0x000F000Fu) | 0x64006400u;
  unsigned u2 = ((w >> 8) & 0x000F000Fu) | 0x64006400u;
  unsigned u3 = ((w >> 12) & 0x000F000Fu) | 0x64006400u;
  uint4 r;
  r.x = __builtin_bit_cast(unsigned, (half2v)((__builtin_bit_cast(half2v, u0) - zh) * sh));
  r.y = __builtin_bit_cast(unsigned, (half2v)((__builtin_bit_cast(half2v, u1) - zh) * sh));
  r.z = __builtin_bit_cast(unsigned, (half2v)((__builtin_bit_cast(half2v, u2) - zh) * sh));
  r.w = __builtin_bit_cast(unsigned, (half2v)((__builtin_bit_cast(half2v, u3) - zh) * sh));
  return __builtin_bit_cast(half8, r);
}

// x fp32 [M][K] -> fragment-ordered fp16: xhp[((kb*(M/32)+rb)*64+lane)]
// lane = (row&31) + 32*(kg&1); 16B per lane in pair order [(0,4),(1,5),(2,6),(3,7)]
__global__ void xperm_kernel(const float* __restrict__ x,
                             uint4* __restrict__ xhp, int M, int K) {
  int t = blockIdx.x * blockDim.x + threadIdx.x;
  int ngrp = K >> 3;
  if (t >= M * ngrp) return;
  int row = t / ngrp, kg = t - row * ngrp;
  const float* src = x + (size_t)row * K + kg * 8;
  float4 f0 = *(const float4*)src, f1 = *(const float4*)(src + 4);
  uint4 q;
  q.x = pkrtz(f0.x, f1.x); q.y = pkrtz(f0.y, f1.y);
  q.z = pkrtz(f0.z, f1.z); q.w = pkrtz(f0.w, f1.w);
  int kb = kg >> 1, l5 = kg & 1, rb = row >> 5;
  int lane = (row & 31) + 32 * l5;
  xhp[((size_t)kb * (M >> 5) + rb) * 64 + lane] = q;
}

__global__ void init_out_kernel(const float* __restrict__ bias,
                                float* __restrict__ out, int MN, int N) {
  int i = (blockIdx.x * blockDim.x + threadIdx.x) * 4;
  if (i < MN) *(float4*)(out + i) = *(const float4*)(bias + (i % N));
}

__global__ void reduce_kernel(const float* __restrict__ ws,
                              const float* __restrict__ bias,
                              float* __restrict__ out, int MN, int N, int S) {
  int i = (blockIdx.x * blockDim.x + threadIdx.x) * 4;
  if (i >= MN) return;
  float4 a = *(const float4*)(bias + (i % N));
  for (int z = 0; z < S; ++z) {
    float4 p = *(const float4*)(ws + (size_t)z * MN + i);
    a.x += p.x; a.y += p.y; a.z += p.z; a.w += p.w;
  }
  *(float4*)(out + i) = a;
}

// Barrier-free, LDS-free wave-level GEMM with STRICT in-order load pipeline.
// Wave tile 32M x 64N; block = 4 waves stacked in M (128 rows); grid (N/64, 1, S).
// Issue order per tile t: A(t+1), zs(g+1), B(t+3); consume A(t), B(t), zs(g) —
// every consumed load is older than all unconsumed prefetches (vmcnt in-order).
template <int NT, int PIPE>
__global__ __launch_bounds__(256) void qgemm_kernel(
    const float* __restrict__ x, const uint4* __restrict__ xhp,
    const int* __restrict__ qw, const int* __restrict__ qz,
    const float* __restrict__ sc, float* __restrict__ target,
    int N, int K, int M32) {
  const int tid = threadIdx.x;
  const int lane = tid & 63;
  const int wid = tid >> 6;          // rb: this wave's 32-row block
  const int l31 = lane & 31;
  const int l5 = lane >> 5;
  const int z = blockIdx.z;
  const int KC = NT * 64;
  const int kbase = z * KC;
  const int kqb = kbase >> 3;
  const int kb0 = kbase >> 4;
  const int N8 = N >> 3;
  const int n0 = blockIdx.x * 64;
  const int c0 = n0 + l31;
  const int c1 = c0 + 32;

  f32x16 acc0 = {}, acc1 = {};

  struct AF { uint4 v[4]; };
  struct BT { unsigned w0[4], w1[4]; };
  struct ZS { unsigned zr0, sr0, zr1, sr1; };
  AF a[2];
  BT b[4];
  ZS zs[2];

  auto LOADA = [&](int t, AF& A) {
    if (PIPE) {
      const uint4* p = xhp + ((size_t)(kb0 + t * 4) * M32 + wid) * 64 + lane;
#pragma unroll
      for (int s = 0; s < 4; ++s) A.v[s] = p[(size_t)s * M32 * 64];
    } else {
      const float* p = x + (size_t)(wid * 32 + l31) * K + kbase + t * 64 + l5 * 8;
#pragma unroll
      for (int s = 0; s < 4; ++s) {
        float4 f0 = *(const float4*)(p + s * 16);
        float4 f1 = *(const float4*)(p + s * 16 + 4);
        uint4 q;
        q.x = pkrtz(f0.x, f1.x); q.y = pkrtz(f0.y, f1.y);
        q.z = pkrtz(f0.z, f1.z); q.w = pkrtz(f0.w, f1.w);
        A.v[s] = q;
      }
    }
  };

  auto LOADB = [&](int t, BT& B) {
    const int* q0 = qw + (size_t)(kqb + t * 8 + l5) * N;
#pragma unroll
    for (int s = 0; s < 4; ++s) {
      B.w0[s] = (unsigned)q0[2 * s * N + c0];
      B.w1[s] = (unsigned)q0[2 * s * N + c1];
    }
  };

  auto LOADZS = [&](int gl, ZS& Z) {
    int g = (kbase >> 7) + gl;
    int zw0 = qz[g * N8 + (c0 >> 3)];
    int zw1 = qz[g * N8 + (c1 >> 3)];
    Z.zr0 = (0x6401u + ((unsigned)(zw0 >> ((c0 & 7) * 4)) & 0xF)) * 0x00010001u;
    Z.zr1 = (0x6401u + ((unsigned)(zw1 >> ((c1 & 7) * 4)) & 0xF)) * 0x00010001u;
    float s0 = sc[g * N + c0], s1 = sc[g * N + c1];
    Z.sr0 = pkrtz(s0, s0);
    Z.sr1 = pkrtz(s1, s1);
  };

  auto TILE = [&](const AF& A, const BT& B, const ZS& Z) {
#pragma unroll
    for (int s = 0; s < 4; ++s) {
      half8 av = __builtin_bit_cast(half8, A.v[s]);
      half8 bf0 = dequant(B.w0[s], Z.zr0, Z.sr0);
      half8 bf1 = dequant(B.w1[s], Z.zr1, Z.sr1);
      acc0 = __builtin_amdgcn_mfma_f32_32x32x16_f16(av, bf0, acc0, 0, 0, 0);
      acc1 = __builtin_amdgcn_mfma_f32_32x32x16_f16(av, bf1, acc1, 0, 0, 0);
    }
  };

  // prologue (issue order: zs0, B0, B1, B2, A0)
  LOADZS(0, zs[0]);
  LOADB(0, b[0]);
  LOADB(1, b[1]);
  LOADB(2, b[2]);
  LOADA(0, a[0]);

#pragma unroll
  for (int t = 0; t < NT; ++t) {
    { int ta = t + 1 < NT ? t + 1 : NT - 1; LOADA(ta, a[(t + 1) & 1]); }
    if ((t & 1) == 0 && (t >> 1) + 1 < NT / 2)
      LOADZS((t >> 1) + 1, zs[((t >> 1) + 1) & 1]);
    { int tb = t + 3 < NT ? t + 3 : NT - 1; LOADB(tb, b[(t + 3) & 3]); }
    TILE(a[t & 1], b[t & 3], zs[(t >> 1) & 1]);
  }

  // epilogue: C/D (32x32): col=lane&31, row=(r&3)+8*(r>>2)+4*(lane>>5)
  if (PIPE) {
    float* o = target + (size_t)z * (size_t)(M32 * 32) * N;
#pragma unroll
    for (int r = 0; r < 16; ++r) {
      int gm = wid * 32 + (r & 3) + 8 * (r >> 2) + 4 * l5;
      o[(size_t)gm * N + c0] = acc0[r];
      o[(size_t)gm * N + c1] = acc1[r];
    }
  } else {
#pragma unroll
    for (int r = 0; r < 16; ++r) {
      int gm = wid * 32 + (r & 3) + 8 * (r >> 2) + 4 * l5;
      unsafeAtomicAdd(&target[(size_t)gm * N + c0], acc0[r]);
      unsafeAtomicAdd(&target[(size_t)gm * N + c1], acc1[r]);
    }
  }
}

extern "C" void kernel_launch(void* const* d_in, const int* in_sizes, int n_in,
                              void* d_out, int out_size, void* d_ws, size_t ws_size,
                              hipStream_t stream) {
  const float* x = (const float*)d_in[0];
  const int* qw = (const int*)d_in[1];
  const int* qz = (const int*)d_in[2];
  const float* sc = (const float*)d_in[3];
  const float* bias = (const float*)d_in[4];
  float* out = (float*)d_out;

  int N = in_sizes[4];
  int K = (in_sizes[1] / N) * 8;
  int M = in_sizes[0] / K;           // 128
  int MN = M * N;
  int MK = M * K;
  int M32 = M >> 5;
  size_t slice = (size_t)MN * 4;
  size_t xh_bytes = (size_t)MK * 2;  // fragment-ordered fp16 x

  int S = 0;
  if (ws_size >= xh_bytes + 8 * slice) S = 8;
  else if (ws_size >= xh_bytes + 4 * slice) S = 4;
  else if (ws_size >= xh_bytes + 2 * slice) S = 2;

  if (S > 0) {
    uint4* xhp = (uint4*)d_ws;
    float* wsl = (float*)((char*)d_ws + xh_bytes);
    xperm_kernel<<<(MK / 8 + 255) / 256, 256, 0, stream>>>(x, xhp, M, K);
    if (S == 8) {
      dim3 grid(N / 64, 1, 8);
      qgemm_kernel<8, 1><<<grid, 256, 0, stream>>>(x, xhp, qw, qz, sc, wsl, N, K, M32);
    } else if (S == 4) {
      dim3 grid(N / 64, 1, 4);
      qgemm_kernel<16, 1><<<grid, 256, 0, stream>>>(x, xhp, qw, qz, sc, wsl, N, K, M32);
    } else {
      dim3 grid(N / 64, 1, 2);
      qgemm_kernel<32, 1><<<grid, 256, 0, stream>>>(x, xhp, qw, qz, sc, wsl, N, K, M32);
    }
    reduce_kernel<<<(MN / 4 + 255) / 256, 256, 0, stream>>>(wsl, bias, out, MN, N, S);
  } else {
    // fallback: atomic accumulate, on-the-fly A conversion (slow but correct)
    init_out_kernel<<<(MN / 4 + 255) / 256, 256, 0, stream>>>(bias, out, MN, N);
    dim3 grid(N / 64, 1, 8);
    qgemm_kernel<8, 0><<<grid, 256, 0, stream>>>(x, (const uint4*)nullptr,
                                                 qw, qz, sc, out, N, K, M32);
  }
}